// Round 3
// baseline (811.289 us; speedup 1.0000x reference)
//
#include <hip/hip_runtime.h>
#include <cmath>
#include <cstdint>

// ---------------------------------------------------------------------------
// MWT for B=32, N=8192, c=16, k=4, modes=64.
// 13 levels: decompose -> fwd truncated-DFT GEMM (bf16 MFMA) -> spectral mix
//            -> inv truncated-DFT GEMM (bf16 MFMA); t0; 13 recon levels.
// Precision plan: x-chain (s-path, t0, recon x) stays fp32; spectral branch
// (twiddles, d/s GEMM inputs, weights, Spec, Ud/Us) is bf16 — contributions
// scaled by ~1/4096 weights, so bf16 error ~1e-5 abs on the output.
// R3: decompose writes the transposed bf16 tensor via LDS tile (coalesced
// dword stores instead of 2-B scatter); weights bf16; twiddles fused to 1 launch.
// ---------------------------------------------------------------------------

typedef __attribute__((ext_vector_type(8))) short bf16x8;
typedef __attribute__((ext_vector_type(4))) float f32x4;

struct Mat84 { float v[8][4]; };
struct Ptrs6 { const float* src[6]; uint16_t* dst[6]; };
struct TwLvls {
  int blkOff[14];
  int Nl[13];
  int l[13];
  unsigned long long fOff[13];
  unsigned long long iOff[13];
};

__device__ __host__ inline uint16_t f2bf(float f) {
  union { float f; uint32_t u; } cv; cv.f = f;
  uint32_t u = cv.u;
  return (uint16_t)((u + 0x7fffu + ((u >> 16) & 1u)) >> 16);
}
__device__ inline float bf2f(uint16_t h) { return __uint_as_float((uint32_t)h << 16); }
__device__ inline uint32_t pack2(float a, float b) {
  return (uint32_t)f2bf(a) | ((uint32_t)f2bf(b) << 16);
}

// ---------------- host: Alpert/Legendre filter construction (k=4) ----------
static double proj_half_h(const double* a, const double* b, bool upper) {
  double prod[7] = {0, 0, 0, 0, 0, 0, 0};
  for (int i = 0; i < 4; i++)
    for (int j = 0; j < 4; j++)
      prod[i + j] += a[i] * b[j];
  for (int n = 0; n < 7; n++)
    if (fabs(prod[n]) < 1e-8) prod[n] = 0.0;
  double s = 0.0;
  for (int n = 0; n < 7; n++) {
    double w = upper ? (1.0 - pow(0.5, n + 1)) / (n + 1) : pow(0.5, n + 1) / (n + 1);
    s += prod[n] * w;
  }
  return s;
}
static double polyval4(const double* c, double x) {
  return c[0] + x * (c[1] + x * (c[2] + x * c[3]));
}

static void compute_filters(Mat84& ecs, Mat84& ecd, Mat84& rce, Mat84& rco) {
  const double leg[4][4] = {{1, 0, 0, 0}, {0, 1, 0, 0}, {-0.5, 0, 1.5, 0}, {0, -1.5, 0, 2.5}};
  double phi_c[4][4] = {}, phi2x_c[4][4] = {};
  const double s2 = sqrt(2.0);
  for (int ki = 0; ki < 4; ki++) {
    double a[4] = {0, 0, 0, 0};
    for (int j = 3; j >= 0; j--) {
      double na[4];
      for (int t = 0; t < 4; t++) { double v = -a[t]; if (t > 0) v += 2.0 * a[t - 1]; na[t] = v; }
      na[0] += leg[ki][j];
      for (int t = 0; t < 4; t++) a[t] = na[t];
    }
    for (int t = 0; t < 4; t++) phi_c[ki][t] = sqrt(2.0 * ki + 1.0) * a[t];
    double bb[4] = {0, 0, 0, 0};
    for (int j = 3; j >= 0; j--) {
      double nb[4];
      for (int t = 0; t < 4; t++) { double v = -bb[t]; if (t > 0) v += 4.0 * bb[t - 1]; nb[t] = v; }
      nb[0] += leg[ki][j];
      for (int t = 0; t < 4; t++) bb[t] = nb[t];
    }
    for (int t = 0; t < 4; t++) phi2x_c[ki][t] = s2 * sqrt(2.0 * ki + 1.0) * bb[t];
  }
  double psi1[4][4] = {}, psi2[4][4] = {};
  for (int ki = 0; ki < 4; ki++) {
    for (int t = 0; t < 4; t++) { psi1[ki][t] = phi2x_c[ki][t]; psi2[ki][t] = 0.0; }
    for (int i = 0; i < 4; i++) {
      double p = proj_half_h(phi2x_c[ki], phi_c[i], false);
      for (int t = 0; t < 4; t++) { psi1[ki][t] -= p * phi_c[i][t]; psi2[ki][t] -= p * phi_c[i][t]; }
    }
    for (int j = 0; j < ki; j++) {
      double p = proj_half_h(phi2x_c[ki], psi1[j], false);
      for (int t = 0; t < 4; t++) { psi1[ki][t] -= p * psi1[j][t]; psi2[ki][t] -= p * psi2[j][t]; }
    }
    double n1 = proj_half_h(psi1[ki], psi1[ki], false);
    double n2 = proj_half_h(psi2[ki], psi2[ki], true);
    double nr = sqrt(n1 + n2);
    for (int t = 0; t < 4; t++) { psi1[ki][t] /= nr; psi2[ki][t] /= nr; }
    for (int t = 0; t < 4; t++) {
      if (fabs(psi1[ki][t]) < 1e-8) psi1[ki][t] = 0.0;
      if (fabs(psi2[ki][t]) < 1e-8) psi2[ki][t] = 0.0;
    }
  }
  const double tq[4] = {-0.8611363115940526, -0.3399810435848563,
                        0.3399810435848563, 0.8611363115940526};
  const double wq[4] = {0.34785484513745385, 0.6521451548625461,
                        0.6521451548625461, 0.34785484513745385};
  double H0[4][4], H1[4][4], G0[4][4], G1[4][4];
  for (int ki = 0; ki < 4; ki++)
    for (int kp = 0; kp < 4; kp++) {
      double h0 = 0, h1 = 0, g0 = 0, g1 = 0;
      for (int m = 0; m < 4; m++) {
        double xm = (tq[m] + 1.0) * 0.5, wm = wq[m] * 0.5;
        double pk = polyval4(phi_c[kp], xm);
        h0 += wm * polyval4(phi_c[ki], xm * 0.5) * pk;
        h1 += wm * polyval4(phi_c[ki], (xm + 1.0) * 0.5) * pk;
        g0 += wm * polyval4(psi1[ki], xm * 0.5) * pk;
        g1 += wm * polyval4(psi2[ki], (xm + 1.0) * 0.5) * pk;
      }
      H0[ki][kp] = h0 / s2; H1[ki][kp] = h1 / s2; G0[ki][kp] = g0 / s2; G1[ki][kp] = g1 / s2;
    }
  for (int i = 0; i < 4; i++)
    for (int j = 0; j < 4; j++) {
      if (fabs(H0[i][j]) < 1e-8) H0[i][j] = 0.0;
      if (fabs(H1[i][j]) < 1e-8) H1[i][j] = 0.0;
      if (fabs(G0[i][j]) < 1e-8) G0[i][j] = 0.0;
      if (fabs(G1[i][j]) < 1e-8) G1[i][j] = 0.0;
    }
  for (int j = 0; j < 4; j++)
    for (int kk = 0; kk < 4; kk++) {
      ecs.v[j][kk]     = (float)H0[kk][j];
      ecs.v[j + 4][kk] = (float)H1[kk][j];
      ecd.v[j][kk]     = (float)G0[kk][j];
      ecd.v[j + 4][kk] = (float)G1[kk][j];
      rce.v[j][kk]     = (float)H0[j][kk];
      rce.v[j + 4][kk] = (float)G0[j][kk];
      rco.v[j][kk]     = (float)H1[j][kk];
      rco.v[j + 4][kk] = (float)G1[j][kk];
    }
}

// ---------------- device kernels -------------------------------------------

// Transpose weights (i,o,m) fp32 -> (m,i,o) bf16.
__global__ void transpose_w(Ptrs6 p) {
  __shared__ float tile[64][65];
  int i = blockIdx.x, a = blockIdx.y;
  const float* w = p.src[a];
  uint16_t* wt = p.dst[a];
  int m = threadIdx.x & 63, orow = threadIdx.x >> 6;
  for (int o = orow; o < 64; o += 4) tile[o][m] = w[((i * 64 + o) << 6) + m];
  __syncthreads();
  int o = threadIdx.x & 63, mrow = threadIdx.x >> 6;
  for (int mm = mrow; mm < 64; mm += 4) wt[((mm * 64 + i) << 6) + o] = f2bf(tile[o][mm]);
}

// All-level twiddles in one launch. Fwd (128 x Nl, rows >= 2l zero) and
// inv (Nl x 128, cols >= 2l zero), both bf16.
__global__ void twiddle_all(uint16_t* __restrict__ FtwB, uint16_t* __restrict__ ItwB,
                            TwLvls tw) {
  int bx = blockIdx.x;
  int L = 0;
  while (L < 12 && bx >= tw.blkOff[L + 1]) L++;
  int Nl = tw.Nl[L], l = tw.l[L];
  int idx = (bx - tw.blkOff[L]) * 256 + threadIdx.x;
  if (idx >= 128 * Nl) return;
  uint16_t* Ftw = FtwB + tw.fOff[L];
  uint16_t* Itw = ItwB + tw.iOff[L];
  int n = idx % Nl, mm = idx / Nl;
  int m = (mm < l) ? mm : mm - l;
  int t = (m * n) & (Nl - 1);
  float ang = 6.2831853071795864769f * ((float)t / (float)Nl);
  float s, c;
  sincosf(ang, &s, &c);
  float fv = 0.f, iv = 0.f;
  float cm = (m == 0 || 2 * m == Nl) ? 1.0f : 2.0f;
  float sc = cm / (float)Nl;
  if (mm < l)          { fv = c;  iv = sc * c; }
  else if (mm < 2 * l) { fv = -s; iv = -sc * s; }
  Ftw[(size_t)mm * Nl + n] = f2bf(fv);
  Itw[(size_t)n * 128 + mm] = f2bf(iv);
}

// Decompose: in (b, 2Nl, 64) fp32 -> s32 (b, Nl, 64) fp32 (x-chain)
//            + dsbfT (b, 128, Nl) bf16, rows 0..63 = d, 64..127 = s.
// Transposed write goes through an LDS tile: each thread computes 4
// consecutive n for one ci, packs bf16 pairs, then blockwise coalesced
// dword stores along n. TILE = min(64, Nl); requires Nl >= 4.
__global__ __launch_bounds__(256) void decompose_kernel(
    const float* __restrict__ xin, float* __restrict__ s32,
    uint16_t* __restrict__ dsbfT, int Nl, int TILE, int lgU,
    Mat84 ecd, Mat84 ecs) {
  __shared__ uint32_t lds[128 * 34];   // [col][pair], stride 34 uints
  int tid = threadIdx.x;
  int tile0 = blockIdx.x * TILE;
  int b = blockIdx.y;
  int ci = tid & 15, nl = tid >> 4;
  if (nl * 4 < TILE) {
    float dall[4][4], sall[4][4];
#pragma unroll
    for (int jj = 0; jj < 4; jj++) {
      int n = tile0 + nl * 4 + jj;
      const float* r0 = xin + ((size_t)(b * 2 * Nl + 2 * n)) * 64 + ci * 4;
      float4 xe = *(const float4*)r0;
      float4 xo = *(const float4*)(r0 + 64);
      float xa[8] = {xe.x, xe.y, xe.z, xe.w, xo.x, xo.y, xo.z, xo.w};
      float d[4] = {0, 0, 0, 0}, s[4] = {0, 0, 0, 0};
#pragma unroll
      for (int j = 0; j < 8; j++) {
        float v = xa[j];
#pragma unroll
        for (int kk = 0; kk < 4; kk++) {
          d[kk] = fmaf(v, ecd.v[j][kk], d[kk]);
          s[kk] = fmaf(v, ecs.v[j][kk], s[kk]);
        }
      }
      *(float4*)&s32[((size_t)b * Nl + n) * 64 + ci * 4] = make_float4(s[0], s[1], s[2], s[3]);
#pragma unroll
      for (int kk = 0; kk < 4; kk++) { dall[jj][kk] = d[kk]; sall[jj][kk] = s[kk]; }
    }
#pragma unroll
    for (int kk = 0; kk < 4; kk++) {
      uint32_t d01 = pack2(dall[0][kk], dall[1][kk]);
      uint32_t d23 = pack2(dall[2][kk], dall[3][kk]);
      uint32_t s01 = pack2(sall[0][kk], sall[1][kk]);
      uint32_t s23 = pack2(sall[2][kk], sall[3][kk]);
      int cd = ci * 4 + kk;
      *(uint2*)&lds[cd * 34 + nl * 2] = make_uint2(d01, d23);
      *(uint2*)&lds[(64 + cd) * 34 + nl * 2] = make_uint2(s01, s23);
    }
  }
  __syncthreads();
  int T2 = TILE >> 1;
  uint32_t* outu = (uint32_t*)dsbfT;
  for (int e = tid; e < 128 * T2; e += 256) {
    int col = e >> lgU, u = e & (T2 - 1);
    uint32_t v = lds[col * 34 + u];
    outu[((((size_t)b * 128 + col) * Nl + tile0) >> 1) + u] = v;
  }
}

// Scalar fallback for Nl < 4 (tiny).
__global__ void decompose_small(const float* __restrict__ xin, float* __restrict__ s32,
                                uint16_t* __restrict__ dsbfT, int Nl,
                                Mat84 ecd, Mat84 ecs) {
  int idx = blockIdx.x * 256 + threadIdx.x;
  int total = 32 * Nl * 16;
  if (idx >= total) return;
  int ci = idx & 15;
  int nb = idx >> 4;
  int n = nb % Nl;
  int b = nb / Nl;
  const float* r0 = xin + ((size_t)(b * 2 * Nl + 2 * n)) * 64 + ci * 4;
  float4 xe = *(const float4*)r0;
  float4 xo = *(const float4*)(r0 + 64);
  float xa[8] = {xe.x, xe.y, xe.z, xe.w, xo.x, xo.y, xo.z, xo.w};
  float d[4] = {0, 0, 0, 0}, s[4] = {0, 0, 0, 0};
#pragma unroll
  for (int j = 0; j < 8; j++) {
    float v = xa[j];
#pragma unroll
    for (int kk = 0; kk < 4; kk++) {
      d[kk] = fmaf(v, ecd.v[j][kk], d[kk]);
      s[kk] = fmaf(v, ecs.v[j][kk], s[kk]);
    }
  }
  *(float4*)&s32[((size_t)b * Nl + n) * 64 + ci * 4] = make_float4(s[0], s[1], s[2], s[3]);
  size_t tb = ((size_t)b * 128 + ci * 4) * Nl + n;
#pragma unroll
  for (int kk = 0; kk < 4; kk++) {
    dsbfT[tb + (size_t)kk * Nl] = f2bf(d[kk]);
    dsbfT[tb + (size_t)(64 + kk) * Nl] = f2bf(s[kk]);
  }
}

// Fwd DFT GEMM (bf16 MFMA): Dfs[z][b] (128x128 fp32) = A(128xK) @ B_b^T(K x 128)
__global__ __launch_bounds__(256) void fwd_mfma(const uint16_t* __restrict__ A,
                                                const uint16_t* __restrict__ BT,
                                                float* __restrict__ Dfs,
                                                int K, int Kchunk) {
  __shared__ uint16_t As[128 * 32];
  __shared__ uint16_t Bs[128 * 32];
  int tid = threadIdx.x;
  int b = blockIdx.x, z = blockIdx.y;
  int k0 = z * Kchunk;
  int k1 = k0 + Kchunk; if (k1 > K) k1 = K;
  const uint16_t* Bb = BT + (size_t)b * 128 * K;
  int w = tid >> 6, lane = tid & 63;
  int wr = w >> 1, wc = w & 1;
  int lr = lane & 15, q = lane >> 4;
  f32x4 acc[4][4];
#pragma unroll
  for (int i = 0; i < 4; i++)
#pragma unroll
    for (int j = 0; j < 4; j++) acc[i][j] = (f32x4){0.f, 0.f, 0.f, 0.f};
  for (int kc = k0; kc < k1; kc += 32) {
    for (int s = tid; s < 512; s += 256) {
      int row = s >> 2, k8 = (s & 3) * 8;
      int kg = kc + k8;
      uint16_t ta[8], tb[8];
      if (kg + 8 <= k1) {
        *(uint4*)ta = *(const uint4*)&A[(size_t)row * K + kg];
        *(uint4*)tb = *(const uint4*)&Bb[(size_t)row * K + kg];
      } else {
#pragma unroll
        for (int j = 0; j < 8; j++) {
          ta[j] = (kg + j < k1) ? A[(size_t)row * K + kg + j] : (uint16_t)0;
          tb[j] = (kg + j < k1) ? Bb[(size_t)row * K + kg + j] : (uint16_t)0;
        }
      }
      *(uint4*)&As[row * 32 + k8] = *(const uint4*)ta;
      *(uint4*)&Bs[row * 32 + k8] = *(const uint4*)tb;
    }
    __syncthreads();
    bf16x8 af[4], bfv[4];
#pragma unroll
    for (int t = 0; t < 4; t++) {
      af[t]  = *(const bf16x8*)&As[(wr * 64 + t * 16 + lr) * 32 + q * 8];
      bfv[t] = *(const bf16x8*)&Bs[(wc * 64 + t * 16 + lr) * 32 + q * 8];
    }
#pragma unroll
    for (int mt = 0; mt < 4; mt++)
#pragma unroll
      for (int nt = 0; nt < 4; nt++)
        acc[mt][nt] = __builtin_amdgcn_mfma_f32_16x16x32_bf16(af[mt], bfv[nt], acc[mt][nt], 0, 0, 0);
    __syncthreads();
  }
  float* Cb = Dfs + ((size_t)z * 32 + b) * 128 * 128;
#pragma unroll
  for (int mt = 0; mt < 4; mt++) {
    int row0 = wr * 64 + mt * 16 + q * 4;
#pragma unroll
    for (int nt = 0; nt < 4; nt++) {
      int col = wc * 64 + nt * 16 + lr;
#pragma unroll
      for (int r = 0; r < 4; r++)
        Cb[(size_t)(row0 + r) * 128 + col] = acc[mt][nt][r];
    }
  }
}

// Spectral mix: sums split-K slabs, per-mode complex mixing (bf16 weights),
// writes Spec transposed bf16 (b, col 128, krow 128).
__global__ __launch_bounds__(256) void middle_kernel(
    const float* __restrict__ Dfs, int nz,
    const uint16_t* __restrict__ wAr, const uint16_t* __restrict__ wAi,
    const uint16_t* __restrict__ wBr, const uint16_t* __restrict__ wBi,
    const uint16_t* __restrict__ wCr, const uint16_t* __restrict__ wCi,
    uint16_t* __restrict__ SpecT, int l) {
  __shared__ float din[4][2][128];
  __shared__ float red[4096];
  int m = blockIdx.x, bg = blockIdx.y;
  int tid = threadIdx.x;
  int o = tid & 63, q = tid >> 6;
  for (int e = tid; e < 1024; e += 256) {
    int col = e & 127, row = (e >> 7) & 1, bb = e >> 8;
    int b = bg * 4 + bb;
    size_t r = row ? (size_t)(l + m) : (size_t)m;
    float s = 0.f;
    for (int z = 0; z < nz; z++)
      s += Dfs[(((size_t)z * 32 + b) * 128 + r) * 128 + col];
    din[bb][row][col] = s;
  }
  __syncthreads();
  float acc[4][4];
#pragma unroll
  for (int i = 0; i < 4; i++)
#pragma unroll
    for (int j = 0; j < 4; j++) acc[i][j] = 0.f;
  for (int ii = 0; ii < 16; ii++) {
    int i = q * 16 + ii;
    size_t widx = ((size_t)(m * 64 + i)) * 64 + o;
    float war = bf2f(wAr[widx]), wai = bf2f(wAi[widx]);
    float wbr = bf2f(wBr[widx]), wbi = bf2f(wBi[widx]);
    float wcr = bf2f(wCr[widx]), wci = bf2f(wCi[widx]);
#pragma unroll
    for (int bb = 0; bb < 4; bb++) {
      float dr = din[bb][0][i], di_ = din[bb][1][i];
      float sr = din[bb][0][64 + i], si = din[bb][1][64 + i];
      acc[bb][0] += dr * war - di_ * wai + sr * wbr - si * wbi;
      acc[bb][1] += dr * wai + di_ * war + sr * wbi + si * wbr;
      acc[bb][2] += dr * wcr - di_ * wci;
      acc[bb][3] += dr * wci + di_ * wcr;
    }
  }
#pragma unroll
  for (int bb = 0; bb < 4; bb++)
#pragma unroll
    for (int v = 0; v < 4; v++) red[((q * 4 + bb) * 4 + v) * 64 + o] = acc[bb][v];
  __syncthreads();
  for (int e = tid; e < 1024; e += 256) {
    int oo = e & 63, v = (e >> 6) & 3, bb = e >> 8;
    float s = red[((0 * 4 + bb) * 4 + v) * 64 + oo] + red[((1 * 4 + bb) * 4 + v) * 64 + oo] +
              red[((2 * 4 + bb) * 4 + v) * 64 + oo] + red[((3 * 4 + bb) * 4 + v) * 64 + oo];
    int b = bg * 4 + bb;
    int krow = (v & 1) ? (l + m) : m;
    int col = (v >= 2) ? 64 + oo : oo;
    SpecT[((size_t)b * 128 + col) * 128 + krow] = f2bf(s);
  }
}

// Inv DFT GEMM (bf16 MFMA): Y_b (Nl x 128) = Itw(Nl x 128) @ Spec_b (128x128).
__global__ __launch_bounds__(256) void inv_mfma(const uint16_t* __restrict__ A,
                                                const uint16_t* __restrict__ SpecT,
                                                uint16_t* __restrict__ Ud,
                                                uint16_t* __restrict__ Us,
                                                int Nl, int K2l) {
  __shared__ uint16_t As[128 * 32];
  __shared__ uint16_t Bs[128 * 32];
  int tid = threadIdx.x;
  int n0 = blockIdx.x * 128, b = blockIdx.y;
  const uint16_t* Bb = SpecT + (size_t)b * 128 * 128;
  int w = tid >> 6, lane = tid & 63;
  int wr = w >> 1, wc = w & 1;
  int lr = lane & 15, q = lane >> 4;
  f32x4 acc[4][4];
#pragma unroll
  for (int i = 0; i < 4; i++)
#pragma unroll
    for (int j = 0; j < 4; j++) acc[i][j] = (f32x4){0.f, 0.f, 0.f, 0.f};
  for (int kc = 0; kc < 128; kc += 32) {
    for (int s = tid; s < 512; s += 256) {
      int row = s >> 2, k8 = (s & 3) * 8;
      int kg = kc + k8;
      *(uint4*)&As[row * 32 + k8] = *(const uint4*)&A[((size_t)(n0 + row)) * 128 + kg];
      uint16_t tb[8];
      if (kg + 8 <= K2l) {
        *(uint4*)tb = *(const uint4*)&Bb[(size_t)row * 128 + kg];
      } else {
#pragma unroll
        for (int j = 0; j < 8; j++)
          tb[j] = (kg + j < K2l) ? Bb[(size_t)row * 128 + kg + j] : (uint16_t)0;
      }
      *(uint4*)&Bs[row * 32 + k8] = *(const uint4*)tb;
    }
    __syncthreads();
    bf16x8 af[4], bfv[4];
#pragma unroll
    for (int t = 0; t < 4; t++) {
      af[t]  = *(const bf16x8*)&As[(wr * 64 + t * 16 + lr) * 32 + q * 8];
      bfv[t] = *(const bf16x8*)&Bs[(wc * 64 + t * 16 + lr) * 32 + q * 8];
    }
#pragma unroll
    for (int mt = 0; mt < 4; mt++)
#pragma unroll
      for (int nt = 0; nt < 4; nt++)
        acc[mt][nt] = __builtin_amdgcn_mfma_f32_16x16x32_bf16(af[mt], bfv[nt], acc[mt][nt], 0, 0, 0);
    __syncthreads();
  }
#pragma unroll
  for (int mt = 0; mt < 4; mt++) {
    int row0 = wr * 64 + mt * 16 + q * 4;
#pragma unroll
    for (int nt = 0; nt < 4; nt++) {
      int col = wc * 64 + nt * 16 + lr;
#pragma unroll
      for (int r = 0; r < 4; r++) {
        int n = n0 + row0 + r;
        if (n < Nl) {
          uint16_t v = f2bf(acc[mt][nt][r]);
          if (col < 64) Ud[((size_t)b * Nl + n) * 64 + col] = v;
          else          Us[((size_t)b * Nl + n) * 64 + (col - 64)] = v;
        }
      }
    }
  }
}

// t0: x(B,1,c,k) @ t0_w^T + t0_b
__global__ void t0_kernel(const float* __restrict__ dsIn, const float* __restrict__ t0w,
                          const float* __restrict__ t0b, float* __restrict__ xout) {
  int idx = blockIdx.x * 256 + threadIdx.x;
  if (idx >= 512) return;
  int ci = idx & 15, b = idx >> 4;
  const float* xp = dsIn + (size_t)b * 64 + ci * 4;
  float x0 = xp[0], x1 = xp[1], x2 = xp[2], x3 = xp[3];
  float* op = xout + (size_t)b * 64 + ci * 4;
#pragma unroll
  for (int kk = 0; kk < 4; kk++)
    op[kk] = x0 * t0w[kk * 4 + 0] + x1 * t0w[kk * 4 + 1] + x2 * t0w[kk * 4 + 2] +
             x3 * t0w[kk * 4 + 3] + t0b[kk];
}

// Reconstruction: t = [x+Us | Ud] (Ud/Us bf16); out[2m]=t@RC_E, out[2m+1]=t@RC_O
__global__ void recon_kernel(const float* __restrict__ x, const uint16_t* __restrict__ Ud,
                             const uint16_t* __restrict__ Us, float* __restrict__ out,
                             int M, int lgM, Mat84 rce, Mat84 rco) {
  int idx = blockIdx.x * 256 + threadIdx.x;
  int ci = idx & 15;
  int nb = idx >> 4;
  int m = nb & (M - 1);
  int b = nb >> lgM;
  if (b >= 32) return;
  size_t basei = ((size_t)b * M + m) * 64 + ci * 4;
  float4 xv = *(const float4*)&x[basei];
  ushort4 uu = *(const ushort4*)&Us[basei];
  ushort4 dd = *(const ushort4*)&Ud[basei];
  float t[8] = {xv.x + bf2f(uu.x), xv.y + bf2f(uu.y), xv.z + bf2f(uu.z), xv.w + bf2f(uu.w),
                bf2f(dd.x), bf2f(dd.y), bf2f(dd.z), bf2f(dd.w)};
  float e[4] = {0, 0, 0, 0}, o[4] = {0, 0, 0, 0};
#pragma unroll
  for (int j = 0; j < 8; j++) {
    float v = t[j];
#pragma unroll
    for (int kk = 0; kk < 4; kk++) {
      e[kk] = fmaf(v, rce.v[j][kk], e[kk]);
      o[kk] = fmaf(v, rco.v[j][kk], o[kk]);
    }
  }
  size_t ob = ((size_t)b * 2 * M + 2 * m) * 64 + ci * 4;
  *(float4*)&out[ob] = make_float4(e[0], e[1], e[2], e[3]);
  *(float4*)&out[ob + 64] = make_float4(o[0], o[1], o[2], o[3]);
}

// ---------------- host orchestration ---------------------------------------
extern "C" void kernel_launch(void* const* d_in, const int* in_sizes, int n_in,
                              void* d_out, int out_size, void* d_ws, size_t ws_size,
                              hipStream_t stream) {
  const float* x_in = (const float*)d_in[0];
  const float* t0w = (const float*)d_in[7];
  const float* t0b = (const float*)d_in[8];

  Mat84 ECS, ECD, RCE, RCO;
  compute_filters(ECS, ECD, RCE, RCO);

  int NlA[13], lA[13];
  size_t fOff[13], iOff[13], uOff[13];
  size_t fo = 0, io = 0, uo = 0;
  for (int L = 0; L < 13; L++) {
    int Nl = 8192 >> (L + 1);
    int l = Nl / 2 + 1; if (l > 64) l = 64;
    NlA[L] = Nl; lA[L] = l;
    fOff[L] = fo; fo += (size_t)128 * Nl;
    iOff[L] = io; io += (size_t)Nl * 128;
    uOff[L] = uo; uo += (size_t)32 * 64 * Nl;
  }
  io += 128 * 128;  // inv_mfma A-staging slack for Nl<128 levels

  char* base = (char*)d_ws;
  size_t off = 0;
  auto alloc = [&](size_t bytes) -> char* {
    char* p = base + off;
    off += (bytes + 255) & ~(size_t)255;
    return p;
  };
  float*    DS0   = (float*)alloc((size_t)32 * 4096 * 64 * 4);
  float*    DS1   = (float*)alloc((size_t)32 * 4096 * 64 * 4);
  uint16_t* Ud    = (uint16_t*)alloc(uo * 2);
  uint16_t* Us    = (uint16_t*)alloc(uo * 2);
  float*    Dfs   = (float*)alloc((size_t)8 * 32 * 128 * 128 * 4);
  uint16_t* SpecT = (uint16_t*)alloc((size_t)32 * 128 * 128 * 2);
  uint16_t* DSbf  = (uint16_t*)alloc((size_t)32 * 128 * 4096 * 2);
  uint16_t* Ftw   = (uint16_t*)alloc(fo * 2);
  uint16_t* Itw   = (uint16_t*)alloc(io * 2);
  uint16_t* wT[6];
  for (int a = 0; a < 6; a++) wT[a] = (uint16_t*)alloc((size_t)64 * 64 * 64 * 2);

  Ptrs6 p6;
  for (int a = 0; a < 6; a++) { p6.src[a] = (const float*)d_in[1 + a]; p6.dst[a] = wT[a]; }
  transpose_w<<<dim3(64, 6), 256, 0, stream>>>(p6);

  TwLvls tw;
  int bo = 0;
  for (int L = 0; L < 13; L++) {
    tw.blkOff[L] = bo;
    bo += (128 * NlA[L] + 255) / 256;
    tw.Nl[L] = NlA[L]; tw.l[L] = lA[L];
    tw.fOff[L] = fOff[L]; tw.iOff[L] = iOff[L];
  }
  tw.blkOff[13] = bo;
  twiddle_all<<<bo, 256, 0, stream>>>(Ftw, Itw, tw);

  // decomposition
  const float* cur = x_in;
  for (int L = 0; L < 13; L++) {
    int Nl = NlA[L], l = lA[L], K = Nl;
    float* s32 = (L & 1) ? DS1 : DS0;
    if (Nl >= 4) {
      int TILE = (Nl < 64) ? Nl : 64;
      int lgU = (31 - __builtin_clz(TILE)) - 1;
      decompose_kernel<<<dim3(Nl / TILE, 32), 256, 0, stream>>>(cur, s32, DSbf, Nl, TILE, lgU,
                                                                ECD, ECS);
    } else {
      int total = 32 * Nl * 16;
      decompose_small<<<(total + 255) / 256, 256, 0, stream>>>(cur, s32, DSbf, Nl, ECD, ECS);
    }
    int nz = K / 64; if (nz < 1) nz = 1; if (nz > 8) nz = 8;
    int Kchunk = (((K + nz - 1) / nz) + 31) & ~31;
    fwd_mfma<<<dim3(32, nz), 256, 0, stream>>>(Ftw + fOff[L], DSbf, Dfs, K, Kchunk);
    middle_kernel<<<dim3(l, 8), 256, 0, stream>>>(Dfs, nz, wT[0], wT[1], wT[2], wT[3], wT[4],
                                                  wT[5], SpecT, l);
    inv_mfma<<<dim3((Nl + 127) / 128, 32), 256, 0, stream>>>(Itw + iOff[L], SpecT,
                                                             Ud + uOff[L], Us + uOff[L],
                                                             Nl, 2 * l);
    cur = s32;
  }

  // coarsest-level linear map: reads DS0 (level-12 s), writes x0 into DS1
  t0_kernel<<<2, 256, 0, stream>>>(DS0, t0w, t0b, DS1);

  // reconstruction (ping-pong DS1/DS0; final level writes d_out)
  float* curx = DS1;
  float* other = DS0;
  for (int i = 12; i >= 0; i--) {
    int M = NlA[i];
    int lg = 31 - __builtin_clz(M);
    float* dst = (i == 0) ? (float*)d_out : other;
    recon_kernel<<<M * 2, 256, 0, stream>>>(curx, Ud + uOff[i], Us + uOff[i], dst, M, lg,
                                            RCE, RCO);
    other = curx; curx = dst;
  }
}

// Round 4
// 417.277 us; speedup vs baseline: 1.9442x; 1.9442x over previous
//
#include <hip/hip_runtime.h>
#include <cmath>
#include <cstdint>

// ---------------------------------------------------------------------------
// MWT for B=32, N=8192, c=16, k=4, modes=64.
// R4 structure (15 dispatches):
//   transpose_w, twiddle_all,
//   dec L0..L3 (per-level), dec_deep (L4..L12 fused pyramid in LDS),
//   fwd_all (all levels, bf16 MFMA), middle_all, inv_all,
//   recon_deep (t0 + i=12..4 fused), recon i=3..0 (per-level).
// Precision: x-chain fp32; spectral branch bf16 (contributions ~1e-3 scale).
// ---------------------------------------------------------------------------

typedef __attribute__((ext_vector_type(8))) short bf16x8;
typedef __attribute__((ext_vector_type(4))) float f32x4;

struct Mat84 { float v[8][4]; };
struct Ptrs6 { const float* src[6]; uint16_t* dst[6]; };
struct TwLvls {
  int blkOff[14]; int Nl[13]; int l[13];
  unsigned long long fOff[13]; unsigned long long iOff[13];
};
struct FwdLvls {
  int blkOff[14]; int K[13]; int Kchunk[13];
  unsigned long long fOff[13]; unsigned long long bOff[13]; unsigned long long dOff[13];
};
struct MidLvls {
  int blkOff[14]; int l[13]; int nz[13];
  unsigned long long dOff[13]; unsigned long long sOff[13];
};
struct InvLvls {
  int blkOff[14]; int Nl[13]; int K2l[13];
  unsigned long long iOff[13]; unsigned long long sOff[13]; unsigned long long uOff[13];
};
struct DeepD { unsigned long long dsbOff[13]; };
struct DeepR { unsigned long long uOff[13]; };

__device__ __host__ inline uint16_t f2bf(float f) {
  union { float f; uint32_t u; } cv; cv.f = f;
  uint32_t u = cv.u;
  return (uint16_t)((u + 0x7fffu + ((u >> 16) & 1u)) >> 16);
}
__device__ inline float bf2f(uint16_t h) { return __uint_as_float((uint32_t)h << 16); }
__device__ inline uint32_t pack2(float a, float b) {
  return (uint32_t)f2bf(a) | ((uint32_t)f2bf(b) << 16);
}

// ---------------- host: Alpert/Legendre filter construction (k=4) ----------
static double proj_half_h(const double* a, const double* b, bool upper) {
  double prod[7] = {0, 0, 0, 0, 0, 0, 0};
  for (int i = 0; i < 4; i++)
    for (int j = 0; j < 4; j++)
      prod[i + j] += a[i] * b[j];
  for (int n = 0; n < 7; n++)
    if (fabs(prod[n]) < 1e-8) prod[n] = 0.0;
  double s = 0.0;
  for (int n = 0; n < 7; n++) {
    double w = upper ? (1.0 - pow(0.5, n + 1)) / (n + 1) : pow(0.5, n + 1) / (n + 1);
    s += prod[n] * w;
  }
  return s;
}
static double polyval4(const double* c, double x) {
  return c[0] + x * (c[1] + x * (c[2] + x * c[3]));
}

static void compute_filters(Mat84& ecs, Mat84& ecd, Mat84& rce, Mat84& rco) {
  const double leg[4][4] = {{1, 0, 0, 0}, {0, 1, 0, 0}, {-0.5, 0, 1.5, 0}, {0, -1.5, 0, 2.5}};
  double phi_c[4][4] = {}, phi2x_c[4][4] = {};
  const double s2 = sqrt(2.0);
  for (int ki = 0; ki < 4; ki++) {
    double a[4] = {0, 0, 0, 0};
    for (int j = 3; j >= 0; j--) {
      double na[4];
      for (int t = 0; t < 4; t++) { double v = -a[t]; if (t > 0) v += 2.0 * a[t - 1]; na[t] = v; }
      na[0] += leg[ki][j];
      for (int t = 0; t < 4; t++) a[t] = na[t];
    }
    for (int t = 0; t < 4; t++) phi_c[ki][t] = sqrt(2.0 * ki + 1.0) * a[t];
    double bb[4] = {0, 0, 0, 0};
    for (int j = 3; j >= 0; j--) {
      double nb[4];
      for (int t = 0; t < 4; t++) { double v = -bb[t]; if (t > 0) v += 4.0 * bb[t - 1]; nb[t] = v; }
      nb[0] += leg[ki][j];
      for (int t = 0; t < 4; t++) bb[t] = nb[t];
    }
    for (int t = 0; t < 4; t++) phi2x_c[ki][t] = s2 * sqrt(2.0 * ki + 1.0) * bb[t];
  }
  double psi1[4][4] = {}, psi2[4][4] = {};
  for (int ki = 0; ki < 4; ki++) {
    for (int t = 0; t < 4; t++) { psi1[ki][t] = phi2x_c[ki][t]; psi2[ki][t] = 0.0; }
    for (int i = 0; i < 4; i++) {
      double p = proj_half_h(phi2x_c[ki], phi_c[i], false);
      for (int t = 0; t < 4; t++) { psi1[ki][t] -= p * phi_c[i][t]; psi2[ki][t] -= p * phi_c[i][t]; }
    }
    for (int j = 0; j < ki; j++) {
      double p = proj_half_h(phi2x_c[ki], psi1[j], false);
      for (int t = 0; t < 4; t++) { psi1[ki][t] -= p * psi1[j][t]; psi2[ki][t] -= p * psi2[j][t]; }
    }
    double n1 = proj_half_h(psi1[ki], psi1[ki], false);
    double n2 = proj_half_h(psi2[ki], psi2[ki], true);
    double nr = sqrt(n1 + n2);
    for (int t = 0; t < 4; t++) { psi1[ki][t] /= nr; psi2[ki][t] /= nr; }
    for (int t = 0; t < 4; t++) {
      if (fabs(psi1[ki][t]) < 1e-8) psi1[ki][t] = 0.0;
      if (fabs(psi2[ki][t]) < 1e-8) psi2[ki][t] = 0.0;
    }
  }
  const double tq[4] = {-0.8611363115940526, -0.3399810435848563,
                        0.3399810435848563, 0.8611363115940526};
  const double wq[4] = {0.34785484513745385, 0.6521451548625461,
                        0.6521451548625461, 0.34785484513745385};
  double H0[4][4], H1[4][4], G0[4][4], G1[4][4];
  for (int ki = 0; ki < 4; ki++)
    for (int kp = 0; kp < 4; kp++) {
      double h0 = 0, h1 = 0, g0 = 0, g1 = 0;
      for (int m = 0; m < 4; m++) {
        double xm = (tq[m] + 1.0) * 0.5, wm = wq[m] * 0.5;
        double pk = polyval4(phi_c[kp], xm);
        h0 += wm * polyval4(phi_c[ki], xm * 0.5) * pk;
        h1 += wm * polyval4(phi_c[ki], (xm + 1.0) * 0.5) * pk;
        g0 += wm * polyval4(psi1[ki], xm * 0.5) * pk;
        g1 += wm * polyval4(psi2[ki], (xm + 1.0) * 0.5) * pk;
      }
      H0[ki][kp] = h0 / s2; H1[ki][kp] = h1 / s2; G0[ki][kp] = g0 / s2; G1[ki][kp] = g1 / s2;
    }
  for (int i = 0; i < 4; i++)
    for (int j = 0; j < 4; j++) {
      if (fabs(H0[i][j]) < 1e-8) H0[i][j] = 0.0;
      if (fabs(H1[i][j]) < 1e-8) H1[i][j] = 0.0;
      if (fabs(G0[i][j]) < 1e-8) G0[i][j] = 0.0;
      if (fabs(G1[i][j]) < 1e-8) G1[i][j] = 0.0;
    }
  for (int j = 0; j < 4; j++)
    for (int kk = 0; kk < 4; kk++) {
      ecs.v[j][kk]     = (float)H0[kk][j];
      ecs.v[j + 4][kk] = (float)H1[kk][j];
      ecd.v[j][kk]     = (float)G0[kk][j];
      ecd.v[j + 4][kk] = (float)G1[kk][j];
      rce.v[j][kk]     = (float)H0[j][kk];
      rce.v[j + 4][kk] = (float)G0[j][kk];
      rco.v[j][kk]     = (float)H1[j][kk];
      rco.v[j + 4][kk] = (float)G1[j][kk];
    }
}

// ---------------- device kernels -------------------------------------------

// Transpose weights (i,o,m) fp32 -> (m,i,o) bf16.
__global__ void transpose_w(Ptrs6 p) {
  __shared__ float tile[64][65];
  int i = blockIdx.x, a = blockIdx.y;
  const float* w = p.src[a];
  uint16_t* wt = p.dst[a];
  int m = threadIdx.x & 63, orow = threadIdx.x >> 6;
  for (int o = orow; o < 64; o += 4) tile[o][m] = w[((i * 64 + o) << 6) + m];
  __syncthreads();
  int o = threadIdx.x & 63, mrow = threadIdx.x >> 6;
  for (int mm = mrow; mm < 64; mm += 4) wt[((mm * 64 + i) << 6) + o] = f2bf(tile[o][mm]);
}

// All-level twiddles. Fwd (128 x Nl, rows >= 2l zero); inv (Nl x 128, cols >= 2l zero).
__global__ void twiddle_all(uint16_t* __restrict__ FtwB, uint16_t* __restrict__ ItwB,
                            TwLvls tw) {
  int bx = blockIdx.x;
  int L = 0;
  while (L < 12 && bx >= tw.blkOff[L + 1]) L++;
  int Nl = tw.Nl[L], l = tw.l[L];
  int idx = (bx - tw.blkOff[L]) * 256 + threadIdx.x;
  if (idx >= 128 * Nl) return;
  uint16_t* Ftw = FtwB + tw.fOff[L];
  uint16_t* Itw = ItwB + tw.iOff[L];
  int n = idx % Nl, mm = idx / Nl;
  int m = (mm < l) ? mm : mm - l;
  int t = (m * n) & (Nl - 1);
  float ang = 6.2831853071795864769f * ((float)t / (float)Nl);
  float s, c;
  sincosf(ang, &s, &c);
  float fv = 0.f, iv = 0.f;
  float cm = (m == 0 || 2 * m == Nl) ? 1.0f : 2.0f;
  float sc = cm / (float)Nl;
  if (mm < l)          { fv = c;  iv = sc * c; }
  else if (mm < 2 * l) { fv = -s; iv = -sc * s; }
  Ftw[(size_t)mm * Nl + n] = f2bf(fv);
  Itw[(size_t)n * 128 + mm] = f2bf(iv);
}

// Decompose one level (Nl >= 512): in (b, 2Nl, 64) fp32 -> s32 (b, Nl, 64) fp32
// + dsbfT (b, 128, Nl) bf16 via LDS transpose tile.
__global__ __launch_bounds__(256) void decompose_kernel(
    const float* __restrict__ xin, float* __restrict__ s32,
    uint16_t* __restrict__ dsbfT, int Nl,
    Mat84 ecd, Mat84 ecs) {
  __shared__ uint32_t lds[128 * 34];
  int tid = threadIdx.x;
  int tile0 = blockIdx.x * 64;
  int b = blockIdx.y;
  int ci = tid & 15, nl = tid >> 4;
  float dall[4][4], sall[4][4];
#pragma unroll
  for (int jj = 0; jj < 4; jj++) {
    int n = tile0 + nl * 4 + jj;
    const float* r0 = xin + ((size_t)(b * 2 * Nl + 2 * n)) * 64 + ci * 4;
    float4 xe = *(const float4*)r0;
    float4 xo = *(const float4*)(r0 + 64);
    float xa[8] = {xe.x, xe.y, xe.z, xe.w, xo.x, xo.y, xo.z, xo.w};
    float d[4] = {0, 0, 0, 0}, s[4] = {0, 0, 0, 0};
#pragma unroll
    for (int j = 0; j < 8; j++) {
      float v = xa[j];
#pragma unroll
      for (int kk = 0; kk < 4; kk++) {
        d[kk] = fmaf(v, ecd.v[j][kk], d[kk]);
        s[kk] = fmaf(v, ecs.v[j][kk], s[kk]);
      }
    }
    *(float4*)&s32[((size_t)b * Nl + n) * 64 + ci * 4] = make_float4(s[0], s[1], s[2], s[3]);
#pragma unroll
    for (int kk = 0; kk < 4; kk++) { dall[jj][kk] = d[kk]; sall[jj][kk] = s[kk]; }
  }
#pragma unroll
  for (int kk = 0; kk < 4; kk++) {
    uint32_t d01 = pack2(dall[0][kk], dall[1][kk]);
    uint32_t d23 = pack2(dall[2][kk], dall[3][kk]);
    uint32_t s01 = pack2(sall[0][kk], sall[1][kk]);
    uint32_t s23 = pack2(sall[2][kk], sall[3][kk]);
    int cd = ci * 4 + kk;
    *(uint2*)&lds[cd * 34 + nl * 2] = make_uint2(d01, d23);
    *(uint2*)&lds[(64 + cd) * 34 + nl * 2] = make_uint2(s01, s23);
  }
  __syncthreads();
  uint32_t* outu = (uint32_t*)dsbfT;
  for (int e = tid; e < 128 * 32; e += 256) {
    int col = e >> 5, u = e & 31;
    uint32_t v = lds[col * 34 + u];
    outu[((((size_t)b * 128 + col) * Nl + tile0) >> 1) + u] = v;
  }
}

// Deep decompose: levels 4..12 fused. Block = (b, c-chunk of 4 c's = 16 cols).
// Reads s^4 (b, 512, 64) fp32; per level writes DSbf slab rows for its cols;
// final s^13 (b, 64) -> sFin.
__global__ __launch_bounds__(256) void dec_deep(const float* __restrict__ sIn,
                                                uint16_t* __restrict__ DSbf,
                                                float* __restrict__ sFin,
                                                DeepD dd, Mat84 ecd, Mat84 ecs) {
  __shared__ float bufA[512 * 17];
  __shared__ float bufB[256 * 17];
  __shared__ uint16_t stg[32 * 256];
  int tid = threadIdx.x;
  int b = blockIdx.x >> 2, cc = blockIdx.x & 3;
  for (int e = tid; e < 512 * 4; e += 256) {
    int n = e >> 2, f4 = e & 3;
    float4 v = *(const float4*)&sIn[((size_t)b * 512 + n) * 64 + cc * 16 + f4 * 4];
    bufA[n * 17 + f4 * 4 + 0] = v.x;
    bufA[n * 17 + f4 * 4 + 1] = v.y;
    bufA[n * 17 + f4 * 4 + 2] = v.z;
    bufA[n * 17 + f4 * 4 + 3] = v.w;
  }
  __syncthreads();
  float* cur = bufA;
  float* nxt = bufB;
  int len = 512;
  for (int L = 4; L <= 12; L++) {
    int M = len >> 1;
    for (int e = tid; e < M * 4; e += 256) {
      int n = e >> 2, cl = e & 3;
      float xa[8];
#pragma unroll
      for (int j = 0; j < 4; j++) {
        xa[j]     = cur[(2 * n) * 17 + cl * 4 + j];
        xa[4 + j] = cur[(2 * n + 1) * 17 + cl * 4 + j];
      }
      float d[4] = {0, 0, 0, 0}, s[4] = {0, 0, 0, 0};
#pragma unroll
      for (int j = 0; j < 8; j++) {
        float v = xa[j];
#pragma unroll
        for (int kk = 0; kk < 4; kk++) {
          d[kk] = fmaf(v, ecd.v[j][kk], d[kk]);
          s[kk] = fmaf(v, ecs.v[j][kk], s[kk]);
        }
      }
#pragma unroll
      for (int kk = 0; kk < 4; kk++) {
        nxt[n * 17 + cl * 4 + kk] = s[kk];
        stg[(cl * 4 + kk) * 256 + n] = f2bf(d[kk]);
        stg[(16 + cl * 4 + kk) * 256 + n] = f2bf(s[kk]);
      }
    }
    __syncthreads();
    uint16_t* out = DSbf + dd.dsbOff[L];
    if (M >= 2) {
      int M2 = M >> 1;
      int lg = 31 - __builtin_clz(M2);
      uint32_t* outu = (uint32_t*)out;
      const uint32_t* stgu = (const uint32_t*)stg;
      for (int e = tid; e < 32 * M2; e += 256) {
        int r = e >> lg, u = e & (M2 - 1);
        int grow = (r < 16) ? (cc * 16 + r) : (64 + cc * 16 + (r - 16));
        outu[(((size_t)b * 128 + grow) * M >> 1) + u] = stgu[r * 128 + u];
      }
    } else {
      for (int e = tid; e < 32; e += 256) {
        int grow = (e < 16) ? (cc * 16 + e) : (64 + cc * 16 + (e - 16));
        out[(size_t)b * 128 + grow] = stg[e * 256];
      }
    }
    __syncthreads();
    float* t = cur; cur = nxt; nxt = t;
    len = M;
  }
  for (int e = tid; e < 16; e += 256) sFin[(size_t)b * 64 + cc * 16 + e] = cur[e];
}

// Fwd DFT GEMM, all levels: Dfs slab (z,b) = Ftw(128xK) @ DSbf_b^T chunk.
__global__ __launch_bounds__(256) void fwd_all(const uint16_t* __restrict__ FtwB,
                                               const uint16_t* __restrict__ DSbfB,
                                               float* __restrict__ DfsB, FwdLvls fl) {
  __shared__ uint16_t As[128 * 32];
  __shared__ uint16_t Bs[128 * 32];
  int bx = blockIdx.x, L = 0;
  while (L < 12 && bx >= fl.blkOff[L + 1]) L++;
  int local = bx - fl.blkOff[L];
  int b = local & 31, z = local >> 5;
  int K = fl.K[L];
  int k0 = z * fl.Kchunk[L];
  int k1 = k0 + fl.Kchunk[L]; if (k1 > K) k1 = K;
  const uint16_t* A = FtwB + fl.fOff[L];
  const uint16_t* Bb = DSbfB + fl.bOff[L] + (size_t)b * 128 * K;
  int tid = threadIdx.x;
  int w = tid >> 6, lane = tid & 63;
  int wr = w >> 1, wc = w & 1;
  int lr = lane & 15, q = lane >> 4;
  f32x4 acc[4][4];
#pragma unroll
  for (int i = 0; i < 4; i++)
#pragma unroll
    for (int j = 0; j < 4; j++) acc[i][j] = (f32x4){0.f, 0.f, 0.f, 0.f};
  for (int kc = k0; kc < k1; kc += 32) {
    for (int s = tid; s < 512; s += 256) {
      int row = s >> 2, k8 = (s & 3) * 8;
      int kg = kc + k8;
      uint16_t ta[8], tb[8];
      if (kg + 8 <= k1) {
        *(uint4*)ta = *(const uint4*)&A[(size_t)row * K + kg];
        *(uint4*)tb = *(const uint4*)&Bb[(size_t)row * K + kg];
      } else {
#pragma unroll
        for (int j = 0; j < 8; j++) {
          ta[j] = (kg + j < k1) ? A[(size_t)row * K + kg + j] : (uint16_t)0;
          tb[j] = (kg + j < k1) ? Bb[(size_t)row * K + kg + j] : (uint16_t)0;
        }
      }
      *(uint4*)&As[row * 32 + k8] = *(const uint4*)ta;
      *(uint4*)&Bs[row * 32 + k8] = *(const uint4*)tb;
    }
    __syncthreads();
    bf16x8 af[4], bfv[4];
#pragma unroll
    for (int t = 0; t < 4; t++) {
      af[t]  = *(const bf16x8*)&As[(wr * 64 + t * 16 + lr) * 32 + q * 8];
      bfv[t] = *(const bf16x8*)&Bs[(wc * 64 + t * 16 + lr) * 32 + q * 8];
    }
#pragma unroll
    for (int mt = 0; mt < 4; mt++)
#pragma unroll
      for (int nt = 0; nt < 4; nt++)
        acc[mt][nt] = __builtin_amdgcn_mfma_f32_16x16x32_bf16(af[mt], bfv[nt], acc[mt][nt], 0, 0, 0);
    __syncthreads();
  }
  float* Cb = DfsB + fl.dOff[L] + ((size_t)z * 32 + b) * 16384;
#pragma unroll
  for (int mt = 0; mt < 4; mt++) {
    int row0 = wr * 64 + mt * 16 + q * 4;
#pragma unroll
    for (int nt = 0; nt < 4; nt++) {
      int col = wc * 64 + nt * 16 + lr;
#pragma unroll
      for (int r = 0; r < 4; r++)
        Cb[(size_t)(row0 + r) * 128 + col] = acc[mt][nt][r];
    }
  }
}

// Spectral mix, all levels: sums split-K slabs, complex mix (bf16 weights),
// writes SpecT (b, col 128, krow 128) bf16 per level.
__global__ __launch_bounds__(256) void middle_all(
    const float* __restrict__ DfsB,
    const uint16_t* __restrict__ wAr, const uint16_t* __restrict__ wAi,
    const uint16_t* __restrict__ wBr, const uint16_t* __restrict__ wBi,
    const uint16_t* __restrict__ wCr, const uint16_t* __restrict__ wCi,
    uint16_t* __restrict__ SpecTB, MidLvls ml) {
  __shared__ float din[4][2][128];
  __shared__ float red[4096];
  int bx = blockIdx.x, L = 0;
  while (L < 12 && bx >= ml.blkOff[L + 1]) L++;
  int local = bx - ml.blkOff[L];
  int m = local >> 3, bg = local & 7;
  int l = ml.l[L], nz = ml.nz[L];
  const float* Dfs = DfsB + ml.dOff[L];
  uint16_t* SpecT = SpecTB + ml.sOff[L];
  int tid = threadIdx.x;
  int o = tid & 63, q = tid >> 6;
  for (int e = tid; e < 1024; e += 256) {
    int col = e & 127, row = (e >> 7) & 1, bb = e >> 8;
    int b = bg * 4 + bb;
    size_t r = row ? (size_t)(l + m) : (size_t)m;
    float s = 0.f;
    for (int z = 0; z < nz; z++)
      s += Dfs[(((size_t)z * 32 + b) * 128 + r) * 128 + col];
    din[bb][row][col] = s;
  }
  __syncthreads();
  float acc[4][4];
#pragma unroll
  for (int i = 0; i < 4; i++)
#pragma unroll
    for (int j = 0; j < 4; j++) acc[i][j] = 0.f;
  for (int ii = 0; ii < 16; ii++) {
    int i = q * 16 + ii;
    size_t widx = ((size_t)(m * 64 + i)) * 64 + o;
    float war = bf2f(wAr[widx]), wai = bf2f(wAi[widx]);
    float wbr = bf2f(wBr[widx]), wbi = bf2f(wBi[widx]);
    float wcr = bf2f(wCr[widx]), wci = bf2f(wCi[widx]);
#pragma unroll
    for (int bb = 0; bb < 4; bb++) {
      float dr = din[bb][0][i], di_ = din[bb][1][i];
      float sr = din[bb][0][64 + i], si = din[bb][1][64 + i];
      acc[bb][0] += dr * war - di_ * wai + sr * wbr - si * wbi;
      acc[bb][1] += dr * wai + di_ * war + sr * wbi + si * wbr;
      acc[bb][2] += dr * wcr - di_ * wci;
      acc[bb][3] += dr * wci + di_ * wcr;
    }
  }
#pragma unroll
  for (int bb = 0; bb < 4; bb++)
#pragma unroll
    for (int v = 0; v < 4; v++) red[((q * 4 + bb) * 4 + v) * 64 + o] = acc[bb][v];
  __syncthreads();
  for (int e = tid; e < 1024; e += 256) {
    int oo = e & 63, v = (e >> 6) & 3, bb = e >> 8;
    float s = red[((0 * 4 + bb) * 4 + v) * 64 + oo] + red[((1 * 4 + bb) * 4 + v) * 64 + oo] +
              red[((2 * 4 + bb) * 4 + v) * 64 + oo] + red[((3 * 4 + bb) * 4 + v) * 64 + oo];
    int b = bg * 4 + bb;
    int krow = (v & 1) ? (l + m) : m;
    int col = (v >= 2) ? 64 + oo : oo;
    SpecT[((size_t)b * 128 + col) * 128 + krow] = f2bf(s);
  }
}

// Inv DFT GEMM, all levels: Y_b (Nl x 128) = Itw(Nl x 128) @ Spec_b (128x128).
__global__ __launch_bounds__(256) void inv_all(const uint16_t* __restrict__ ItwB,
                                               const uint16_t* __restrict__ SpecTB,
                                               uint16_t* __restrict__ UdB,
                                               uint16_t* __restrict__ UsB, InvLvls il) {
  __shared__ uint16_t As[128 * 32];
  __shared__ uint16_t Bs[128 * 32];
  int bx = blockIdx.x, L = 0;
  while (L < 12 && bx >= il.blkOff[L + 1]) L++;
  int local = bx - il.blkOff[L];
  int b = local & 31, n0 = (local >> 5) * 128;
  int Nl = il.Nl[L], K2l = il.K2l[L];
  const uint16_t* A = ItwB + il.iOff[L];
  const uint16_t* Bb = SpecTB + il.sOff[L] + (size_t)b * 128 * 128;
  uint16_t* Ud = UdB + il.uOff[L];
  uint16_t* Us = UsB + il.uOff[L];
  int tid = threadIdx.x;
  int w = tid >> 6, lane = tid & 63;
  int wr = w >> 1, wc = w & 1;
  int lr = lane & 15, q = lane >> 4;
  f32x4 acc[4][4];
#pragma unroll
  for (int i = 0; i < 4; i++)
#pragma unroll
    for (int j = 0; j < 4; j++) acc[i][j] = (f32x4){0.f, 0.f, 0.f, 0.f};
  for (int kc = 0; kc < 128; kc += 32) {
    for (int s = tid; s < 512; s += 256) {
      int row = s >> 2, k8 = (s & 3) * 8;
      int kg = kc + k8;
      *(uint4*)&As[row * 32 + k8] = *(const uint4*)&A[((size_t)(n0 + row)) * 128 + kg];
      uint16_t tb[8];
      if (kg + 8 <= K2l) {
        *(uint4*)tb = *(const uint4*)&Bb[(size_t)row * 128 + kg];
      } else {
#pragma unroll
        for (int j = 0; j < 8; j++)
          tb[j] = (kg + j < K2l) ? Bb[(size_t)row * 128 + kg + j] : (uint16_t)0;
      }
      *(uint4*)&Bs[row * 32 + k8] = *(const uint4*)tb;
    }
    __syncthreads();
    bf16x8 af[4], bfv[4];
#pragma unroll
    for (int t = 0; t < 4; t++) {
      af[t]  = *(const bf16x8*)&As[(wr * 64 + t * 16 + lr) * 32 + q * 8];
      bfv[t] = *(const bf16x8*)&Bs[(wc * 64 + t * 16 + lr) * 32 + q * 8];
    }
#pragma unroll
    for (int mt = 0; mt < 4; mt++)
#pragma unroll
      for (int nt = 0; nt < 4; nt++)
        acc[mt][nt] = __builtin_amdgcn_mfma_f32_16x16x32_bf16(af[mt], bfv[nt], acc[mt][nt], 0, 0, 0);
    __syncthreads();
  }
#pragma unroll
  for (int mt = 0; mt < 4; mt++) {
    int row0 = wr * 64 + mt * 16 + q * 4;
#pragma unroll
    for (int nt = 0; nt < 4; nt++) {
      int col = wc * 64 + nt * 16 + lr;
#pragma unroll
      for (int r = 0; r < 4; r++) {
        int n = n0 + row0 + r;
        if (n < Nl) {
          uint16_t v = f2bf(acc[mt][nt][r]);
          if (col < 64) Ud[((size_t)b * Nl + n) * 64 + col] = v;
          else          Us[((size_t)b * Nl + n) * 64 + (col - 64)] = v;
        }
      }
    }
  }
}

// Deep recon: t0 on s^13, then levels i=12..4 fused; writes x^4 (b, 512, 64) fp32.
__global__ __launch_bounds__(256) void recon_deep(const float* __restrict__ sFin,
                                                  const float* __restrict__ t0w,
                                                  const float* __restrict__ t0b,
                                                  const uint16_t* __restrict__ UdB,
                                                  const uint16_t* __restrict__ UsB,
                                                  float* __restrict__ xOut,
                                                  DeepR rl, Mat84 rce, Mat84 rco) {
  __shared__ float bufA[512 * 17];
  __shared__ float bufB[256 * 17];
  int tid = threadIdx.x;
  int b = blockIdx.x >> 2, cc = blockIdx.x & 3;
  if (tid < 16) {
    int cl = tid >> 2, kk = tid & 3;
    const float* sp = sFin + (size_t)b * 64 + cc * 16 + cl * 4;
    float v = t0b[kk];
#pragma unroll
    for (int k2 = 0; k2 < 4; k2++) v += t0w[kk * 4 + k2] * sp[k2];
    bufB[cl * 4 + kk] = v;
  }
  __syncthreads();
  float* cur = bufB;
  float* nxt = bufA;
  int M = 1;
  for (int i = 12; i >= 4; i--) {
    const uint16_t* Ud = UdB + rl.uOff[i];
    const uint16_t* Us = UsB + rl.uOff[i];
    for (int e = tid; e < M * 4; e += 256) {
      int n = e >> 2, cl = e & 3;
      size_t ua = ((size_t)b * M + n) * 64 + cc * 16 + cl * 4;
      ushort4 uu = *(const ushort4*)&Us[ua];
      ushort4 dd = *(const ushort4*)&Ud[ua];
      float t[8];
      t[0] = cur[n * 17 + cl * 4 + 0] + bf2f(uu.x);
      t[1] = cur[n * 17 + cl * 4 + 1] + bf2f(uu.y);
      t[2] = cur[n * 17 + cl * 4 + 2] + bf2f(uu.z);
      t[3] = cur[n * 17 + cl * 4 + 3] + bf2f(uu.w);
      t[4] = bf2f(dd.x); t[5] = bf2f(dd.y); t[6] = bf2f(dd.z); t[7] = bf2f(dd.w);
      float ev[4] = {0, 0, 0, 0}, ov[4] = {0, 0, 0, 0};
#pragma unroll
      for (int j = 0; j < 8; j++) {
        float v = t[j];
#pragma unroll
        for (int kk = 0; kk < 4; kk++) {
          ev[kk] = fmaf(v, rce.v[j][kk], ev[kk]);
          ov[kk] = fmaf(v, rco.v[j][kk], ov[kk]);
        }
      }
#pragma unroll
      for (int kk = 0; kk < 4; kk++) {
        nxt[(2 * n) * 17 + cl * 4 + kk] = ev[kk];
        nxt[(2 * n + 1) * 17 + cl * 4 + kk] = ov[kk];
      }
    }
    __syncthreads();
    float* t = cur; cur = nxt; nxt = t;
    M <<= 1;
  }
  for (int e = tid; e < 512 * 4; e += 256) {
    int n = e >> 2, f4 = e & 3;
    float4 v = make_float4(cur[n * 17 + f4 * 4 + 0], cur[n * 17 + f4 * 4 + 1],
                           cur[n * 17 + f4 * 4 + 2], cur[n * 17 + f4 * 4 + 3]);
    *(float4*)&xOut[((size_t)b * 512 + n) * 64 + cc * 16 + f4 * 4] = v;
  }
}

// Recon one level: t = [x+Us | Ud]; out[2m]=t@RC_E, out[2m+1]=t@RC_O
__global__ void recon_kernel(const float* __restrict__ x, const uint16_t* __restrict__ Ud,
                             const uint16_t* __restrict__ Us, float* __restrict__ out,
                             int M, int lgM, Mat84 rce, Mat84 rco) {
  int idx = blockIdx.x * 256 + threadIdx.x;
  int ci = idx & 15;
  int nb = idx >> 4;
  int m = nb & (M - 1);
  int b = nb >> lgM;
  if (b >= 32) return;
  size_t basei = ((size_t)b * M + m) * 64 + ci * 4;
  float4 xv = *(const float4*)&x[basei];
  ushort4 uu = *(const ushort4*)&Us[basei];
  ushort4 dd = *(const ushort4*)&Ud[basei];
  float t[8] = {xv.x + bf2f(uu.x), xv.y + bf2f(uu.y), xv.z + bf2f(uu.z), xv.w + bf2f(uu.w),
                bf2f(dd.x), bf2f(dd.y), bf2f(dd.z), bf2f(dd.w)};
  float e[4] = {0, 0, 0, 0}, o[4] = {0, 0, 0, 0};
#pragma unroll
  for (int j = 0; j < 8; j++) {
    float v = t[j];
#pragma unroll
    for (int kk = 0; kk < 4; kk++) {
      e[kk] = fmaf(v, rce.v[j][kk], e[kk]);
      o[kk] = fmaf(v, rco.v[j][kk], o[kk]);
    }
  }
  size_t ob = ((size_t)b * 2 * M + 2 * m) * 64 + ci * 4;
  *(float4*)&out[ob] = make_float4(e[0], e[1], e[2], e[3]);
  *(float4*)&out[ob + 64] = make_float4(o[0], o[1], o[2], o[3]);
}

// ---------------- host orchestration ---------------------------------------
extern "C" void kernel_launch(void* const* d_in, const int* in_sizes, int n_in,
                              void* d_out, int out_size, void* d_ws, size_t ws_size,
                              hipStream_t stream) {
  const float* x_in = (const float*)d_in[0];
  const float* t0w = (const float*)d_in[7];
  const float* t0b = (const float*)d_in[8];

  Mat84 ECS, ECD, RCE, RCO;
  compute_filters(ECS, ECD, RCE, RCO);

  int NlA[13], lA[13], nzA[13], KchA[13];
  size_t fOff[13], iOff[13], uOffA[13], dsbOff[13], dOff[13], sOff[13];
  size_t fo = 0, io = 0, uo = 0, db = 0, df = 0;
  for (int L = 0; L < 13; L++) {
    int Nl = 8192 >> (L + 1);
    int l = Nl / 2 + 1; if (l > 64) l = 64;
    NlA[L] = Nl; lA[L] = l;
    nzA[L] = (L == 0) ? 4 : (L == 1) ? 2 : 1;
    KchA[L] = Nl / nzA[L];
    fOff[L] = fo; fo += (size_t)128 * Nl;
    iOff[L] = io; io += (size_t)Nl * 128;
    uOffA[L] = uo; uo += (size_t)32 * 64 * Nl;
    dsbOff[L] = db; db += (size_t)32 * 128 * Nl;
    dOff[L] = df; df += (size_t)nzA[L] * 32 * 128 * 128;
    sOff[L] = (size_t)L * 32 * 128 * 128;
  }
  io += 128 * 128;  // inv_all A-row overrun slack at partial tiles

  char* base = (char*)d_ws;
  size_t off = 0;
  auto alloc = [&](size_t bytes) -> char* {
    char* p = base + off;
    off += (bytes + 255) & ~(size_t)255;
    return p;
  };
  float*    SA    = (float*)alloc((size_t)32 * 4096 * 64 * 4);
  float*    SB    = (float*)alloc((size_t)32 * 2048 * 64 * 4);
  float*    SC    = (float*)alloc((size_t)32 * 1024 * 64 * 4);
  float*    SD    = (float*)alloc((size_t)32 * 512 * 64 * 4);
  float*    SFin  = (float*)alloc((size_t)32 * 64 * 4);
  uint16_t* Ud    = (uint16_t*)alloc(uo * 2);
  uint16_t* Us    = (uint16_t*)alloc(uo * 2);
  float*    Dfs   = (float*)alloc(df * 4);
  uint16_t* SpecT = (uint16_t*)alloc((size_t)13 * 32 * 128 * 128 * 2);
  uint16_t* DSbf  = (uint16_t*)alloc(db * 2);
  uint16_t* Ftw   = (uint16_t*)alloc(fo * 2);
  uint16_t* Itw   = (uint16_t*)alloc(io * 2);
  uint16_t* wT[6];
  for (int a = 0; a < 6; a++) wT[a] = (uint16_t*)alloc((size_t)64 * 64 * 64 * 2);

  // 1: weights
  Ptrs6 p6;
  for (int a = 0; a < 6; a++) { p6.src[a] = (const float*)d_in[1 + a]; p6.dst[a] = wT[a]; }
  transpose_w<<<dim3(64, 6), 256, 0, stream>>>(p6);

  // 2: twiddles
  TwLvls tw;
  int bo = 0;
  for (int L = 0; L < 13; L++) {
    tw.blkOff[L] = bo;
    bo += (128 * NlA[L] + 255) / 256;
    tw.Nl[L] = NlA[L]; tw.l[L] = lA[L];
    tw.fOff[L] = fOff[L]; tw.iOff[L] = iOff[L];
  }
  tw.blkOff[13] = bo;
  twiddle_all<<<bo, 256, 0, stream>>>(Ftw, Itw, tw);

  // 3-6: decompose L0..L3
  {
    const float* srcs[4] = {x_in, SA, SB, SC};
    float* dsts[4] = {SA, SB, SC, SD};
    for (int L = 0; L < 4; L++) {
      int Nl = NlA[L];
      decompose_kernel<<<dim3(Nl / 64, 32), 256, 0, stream>>>(srcs[L], dsts[L],
                                                              DSbf + dsbOff[L], Nl, ECD, ECS);
    }
  }

  // 7: deep decompose L4..L12
  DeepD dd;
  for (int L = 0; L < 13; L++) dd.dsbOff[L] = dsbOff[L];
  dec_deep<<<128, 256, 0, stream>>>(SD, DSbf, SFin, dd, ECD, ECS);

  // 8: fwd GEMM all levels
  FwdLvls fl;
  bo = 0;
  for (int L = 0; L < 13; L++) {
    fl.blkOff[L] = bo; bo += 32 * nzA[L];
    fl.K[L] = NlA[L]; fl.Kchunk[L] = KchA[L];
    fl.fOff[L] = fOff[L]; fl.bOff[L] = dsbOff[L]; fl.dOff[L] = dOff[L];
  }
  fl.blkOff[13] = bo;
  fwd_all<<<bo, 256, 0, stream>>>(Ftw, DSbf, Dfs, fl);

  // 9: spectral mix all levels
  MidLvls ml;
  bo = 0;
  for (int L = 0; L < 13; L++) {
    ml.blkOff[L] = bo; bo += lA[L] * 8;
    ml.l[L] = lA[L]; ml.nz[L] = nzA[L];
    ml.dOff[L] = dOff[L]; ml.sOff[L] = sOff[L];
  }
  ml.blkOff[13] = bo;
  middle_all<<<bo, 256, 0, stream>>>(Dfs, wT[0], wT[1], wT[2], wT[3], wT[4], wT[5], SpecT, ml);

  // 10: inv GEMM all levels
  InvLvls il;
  bo = 0;
  for (int L = 0; L < 13; L++) {
    il.blkOff[L] = bo; bo += ((NlA[L] + 127) / 128) * 32;
    il.Nl[L] = NlA[L]; il.K2l[L] = 2 * lA[L];
    il.iOff[L] = iOff[L]; il.sOff[L] = sOff[L]; il.uOff[L] = uOffA[L];
  }
  il.blkOff[13] = bo;
  inv_all<<<bo, 256, 0, stream>>>(Itw, SpecT, Ud, Us, il);

  // 11: deep recon (t0 + i=12..4) -> x^4 in SD
  DeepR rl;
  for (int L = 0; L < 13; L++) rl.uOff[L] = uOffA[L];
  recon_deep<<<128, 256, 0, stream>>>(SFin, t0w, t0b, Ud, Us, SD, rl, RCE, RCO);

  // 12-15: recon i=3..0
  {
    float* xs[4] = {SD, SC, SB, SA};
    float* outs[4] = {SC, SB, SA, (float*)d_out};
    for (int t = 0; t < 4; t++) {
      int i = 3 - t;
      int M = NlA[i];
      int lg = 31 - __builtin_clz(M);
      recon_kernel<<<M * 2, 256, 0, stream>>>(xs[t], Ud + uOffA[i], Us + uOffA[i], outs[t],
                                              M, lg, RCE, RCO);
    }
  }
}